// Round 12
// baseline (37.359 us; speedup 1.0000x reference)
//
#include <hip/hip_runtime.h>

#define B_ 8
#define C_ 256
#define S_ 2048
#define T_ (B_*S_)      // 16384 tokens

typedef short s8v __attribute__((ext_vector_type(8)));
typedef short s4v __attribute__((ext_vector_type(4)));
typedef float f4v __attribute__((ext_vector_type(4)));

__device__ inline short f2b(float f){            // fp32 -> bf16 RNE
  unsigned u = __builtin_bit_cast(unsigned, f);
  unsigned r = (u + 0x7FFFu + ((u >> 16) & 1u)) >> 16;
  return (short)r;
}
__device__ inline float b2f(short s){
  unsigned u = ((unsigned)(unsigned short)s) << 16;
  return __builtin_bit_cast(float, u);
}

// async global->LDS, 16B/lane; LDS dest = wave-uniform base + lane*16
__device__ inline void glds16(const void* g, void* l){
  __builtin_amdgcn_global_load_lds(
      (const __attribute__((address_space(1))) unsigned int*)g,
      (__attribute__((address_space(3))) unsigned int*)l, 16, 0, 0);
}

// K1: fused prep, 1216 blocks, no global atomics.
//  0-1023:    x (B,C,S) fp32 -> xT token-major bf16 (proven transpose)
//  1024-1151: weight (R,C,M) fp32 -> wT2 bf16 tiled [r][kc 8][n 256][k32]
//  1152-1215: counting sort per 128-token segment (2 segments per block),
//             segBucket[seg*128..] e-sorted tokens, segCnt[seg][e]; idx passthrough.
__global__ __launch_bounds__(256) void k_pre(const float* __restrict__ x, short* __restrict__ xT,
                                             const float* __restrict__ wgt, short* __restrict__ wT2,
                                             const int* __restrict__ idx, int* __restrict__ segCnt,
                                             int* __restrict__ segBucket, float* __restrict__ idx_out){
  __shared__ float tile[64][65];
  int tid = threadIdx.x;
  int bid = blockIdx.x;

  if (bid < 1024){
    int b  = bid >> 7;
    int ct = (bid >> 5) & 3;
    int st = bid & 31;
    const float* xb = x + b*(C_*S_);
    #pragma unroll
    for (int it = 0; it < 4; ++it){
      int row = it*16 + (tid >> 4);       // c-local
      int s4  = tid & 15;
      float4 v = *(const float4*)(xb + (ct*64 + row)*S_ + st*64 + s4*4);
      tile[row][s4*4+0] = v.x; tile[row][s4*4+1] = v.y;
      tile[row][s4*4+2] = v.z; tile[row][s4*4+3] = v.w;
    }
    __syncthreads();
    #pragma unroll
    for (int it = 0; it < 4; ++it){
      int srow = it*16 + (tid >> 4);      // s-local
      int c4   = tid & 15;
      s4v o;
      o[0] = f2b(tile[c4*4+0][srow]); o[1] = f2b(tile[c4*4+1][srow]);
      o[2] = f2b(tile[c4*4+2][srow]); o[3] = f2b(tile[c4*4+3][srow]);
      *(s4v*)(xT + (b*S_ + st*64 + srow)*C_ + ct*64 + c4*4) = o;
    }
  } else if (bid < 1152){
    int wb_ = bid - 1024;
    int r  = wb_ >> 4;
    int ct = (wb_ >> 2) & 3;   // c-tile (K dim)
    int mt = wb_ & 3;          // n-tile
    const float* wsrc = wgt + r*(C_*256);
    #pragma unroll
    for (int it = 0; it < 4; ++it){
      int row = it*16 + (tid >> 4);       // c-local
      int m4  = tid & 15;
      float4 v = *(const float4*)(wsrc + (ct*64 + row)*256 + mt*64 + m4*4);
      tile[row][m4*4+0] = v.x; tile[row][m4*4+1] = v.y;
      tile[row][m4*4+2] = v.z; tile[row][m4*4+3] = v.w;
    }
    __syncthreads();
    char* wdst = (char*)wT2 + r*131072;
    #pragma unroll
    for (int it = 0; it < 2; ++it){
      int q  = it*256 + tid;
      int ml = q >> 3;                    // n-local
      int ck = q & 7;                     // 8 consecutive c
      int mg = mt*64 + ml;
      int cg = ct*64 + ck*8;
      int kcb = cg >> 5, klocal = cg & 31;
      s8v o;
      #pragma unroll
      for (int j = 0; j < 8; ++j) o[j] = f2b(tile[ck*8 + j][ml]);
      *(s8v*)(wdst + kcb*16384 + mg*64 + klocal*2) = o;   // linear [kc][n][k32]
    }
  } else {
    int blk = bid - 1152;                 // 0..63, two 128-token segments each
    __shared__ int lcount[2][8], lbase2[2][8];
    int h  = tid >> 7;                    // segment half 0/1
    int lt = tid & 127;
    int seg = blk*2 + h;
    if (lt < 8) lcount[h][lt] = 0;
    __syncthreads();
    int t  = seg*128 + lt;
    int ei = idx[t];
    int e  = ei & 7;
    int lp = atomicAdd(&lcount[h][e], 1); // LDS atomic, block-local
    __syncthreads();
    if (lt == 0){
      int a0 = 0;
      #pragma unroll
      for (int e2 = 0; e2 < 8; ++e2){ lbase2[h][e2] = a0; a0 += lcount[h][e2]; }
    }
    __syncthreads();
    if (lt < 8) segCnt[seg*8 + lt] = lcount[h][lt];
    segBucket[seg*128 + lbase2[h][e] + lp] = t;
    idx_out[t] = (float)ei;
  }
}

// K2: fused GEMM+finalize. Block = (128-token segment, 64-col quarter), grid 512
// (2 blocks/CU, LDS 54KB). bid maps 4 quarters of a segment to one XCD (xT L2 reuse).
// Per block: sorted slot list; 4 sub-tiles of 32 rows, A double-buffered via
// global_load_lds(16) with pre-swizzled gather source (one barrier per sub-tile);
// K-loop barrier-free, B direct global->VGPR from L2-resident wT2; mixed-expert
// 16-row groups via per-row cndmask merge; epilogue (bias+residual+rate-mask, bf16)
// lands in OS[64c][128s] -> final fp32 outx/outm writes are 512B s-runs. No yT.
__global__ __launch_bounds__(256,2) void k_main(const short* __restrict__ xT, const short* __restrict__ wT2,
                                                const float* __restrict__ bias, const int* __restrict__ segCnt,
                                                const int* __restrict__ segBucket, const int* __restrict__ rate,
                                                float* __restrict__ outx, float* __restrict__ outm){
  int bid = blockIdx.x;
  int q   = (bid >> 3) & 3;
  int seg = (bid & 7) | ((bid >> 5) << 3);
  int b   = seg >> 4;
  int s0  = (seg & 15) << 7;

  __shared__ short A[2][32*256];   // 2 x 16KB, XOR ((row&7)<<4) within 512B rows
  __shared__ short OS[64*136];     // 17KB out-stage [c-local][s-local], stride 136
  __shared__ float biasQ[8*64];
  __shared__ int slocal8[128];     // slot -> s-local
  __shared__ int eSlot[128];       // slot -> expert
  __shared__ int maskR[128];       // s-local -> rate>>5
  __shared__ int eRangeG[8];       // 16-row group -> elo|ehi<<8
  __shared__ int rateE[8];
  __shared__ int cum[9];

  int tid = threadIdx.x, lane = tid & 63, wv = tid >> 6;
  int l15 = lane & 15, lq = lane >> 4;

  if (tid < 8) rateE[tid] = rate[tid];
  { int e = tid >> 5, j = (tid & 31)*2;
    float2 bv2 = *(const float2*)(bias + e*256 + q*64 + j);
    biasQ[e*64 + j] = bv2.x; biasQ[e*64 + j + 1] = bv2.y; }
  if (tid == 0){
    int a0 = 0; cum[0] = 0;
    #pragma unroll
    for (int e2 = 0; e2 < 8; ++e2){ a0 += segCnt[seg*8 + e2]; cum[e2+1] = a0; }
  }
  __syncthreads();
  if (tid < 128){
    int t  = segBucket[seg*128 + tid];
    int sl = t & 127;
    int e  = 0;
    #pragma unroll
    for (int j = 1; j < 8; ++j) e += (tid >= cum[j]);
    slocal8[tid] = sl;
    eSlot[tid]   = e;
    maskR[sl]    = rateE[e] >> 5;
  }
  __syncthreads();
  if (tid < 8) eRangeG[tid] = eSlot[tid*16] | (eSlot[tid*16 + 15] << 8);
  // eRangeG first read after the loop-top barrier below.

  const char* xTb = (const char*)xT;
  auto STAGE = [&](int bufi, int sub){
    #pragma unroll
    for (int j = 0; j < 4; ++j){
      int base = wv*4096 + j*1024;               // wave-uniform LDS dest base
      int row  = wv*8 + j*2 + (lane >> 5);       // buffer-local row of this lane's 16B
      int tok  = seg*128 + slocal8[sub*32 + row];
      int off  = (lane & 31)*16;
      glds16(xTb + tok*512 + (off ^ ((row & 7) << 4)), (char*)A[bufi] + base);
    }
  };

  STAGE(0, 0);
  int cur = 0;
  int cg  = q*64 + wv*16 + l15;                  // lane's output column (global c)
  float bsE[8];                                  // not used; bias via LDS below
  (void)bsE;

  for (int sub = 0; sub < 4; ++sub){
    __syncthreads();                             // drains glds of buf[cur]; prev readers done
    if (sub < 3) STAGE(cur ^ 1, sub + 1);

    const char* ABc = (const char*)A[cur];
    s8v aF[2][8];
    int aswz = (l15 & 7) << 4;
    #pragma unroll
    for (int kc = 0; kc < 8; ++kc){
      aF[0][kc] = *(const s8v*)(ABc + l15*512        + ((kc*64 + lq*16) ^ aswz));
      aF[1][kc] = *(const s8v*)(ABc + (16 + l15)*512 + ((kc*64 + lq*16) ^ aswz));
    }

    #pragma unroll
    for (int mi = 0; mi < 2; ++mi){
      int g  = sub*2 + mi;
      int rg = eRangeG[g], elo = rg & 255, ehi = rg >> 8;
      int qb = sub*32 + mi*16 + lq*4;
      int epk = eSlot[qb] | (eSlot[qb+1] << 8) | (eSlot[qb+2] << 16) | (eSlot[qb+3] << 24);
      f4v acc = (f4v){0.f,0.f,0.f,0.f};
      for (int e = elo; e <= ehi; ++e){
        const char* bp = (const char*)wT2 + e*131072 + cg*64 + lq*16;
        f4v t = (f4v){0.f,0.f,0.f,0.f};
        #pragma unroll
        for (int kc = 0; kc < 8; ++kc){
          s8v bv = *(const s8v*)(bp + kc*16384);
          t = __builtin_amdgcn_mfma_f32_16x16x32_bf16(aF[mi][kc], bv, t, 0, 0, 0);
        }
        float bs = biasQ[e*64 + wv*16 + l15];
        #pragma unroll
        for (int r = 0; r < 4; ++r){
          bool hit = (((epk >> (r*8)) & 255) == e);   // exactly one e per row
          acc[r] = hit ? (t[r] + bs) : acc[r];
        }
      }
      // epilogue for this 16-row group -> OS (bf16), unpermuted to s-local
      #pragma unroll
      for (int r = 0; r < 4; ++r){
        int rowL = mi*16 + lq*4 + r;               // buffer-local row
        int sl   = slocal8[sub*32 + rowL];
        int er   = (epk >> (r*8)) & 255;
        float xres = b2f(*(const short*)(ABc + rowL*512 + ((cg*2) ^ ((rowL & 7) << 4))));
        float val  = (cg < rateE[er]) ? (acc[r] + xres) : 0.0f;
        OS[(wv*16 + l15)*136 + sl] = f2b(val);
      }
    }
    cur ^= 1;
  }
  __syncthreads();

  // ---- final write: 64 c-rows x 128 s, fp32, 512B contiguous runs ----
  {
    float* ob = outx + b*(C_*S_) + s0;
    float* om = outm + b*(C_*S_) + s0;
    #pragma unroll
    for (int it = 0; it < 8; ++it){
      int q2 = it*256 + tid;
      int cl = q2 >> 5;                 // 0..63
      int s4 = (q2 & 31)*4;             // 0..124
      s4v v = *(const s4v*)((const char*)OS + cl*272 + s4*2);
      int cgl = q*64 + cl;
      int mk  = cgl >> 5;
      float4 ov, mv;
      ov.x = b2f(v[0]); ov.y = b2f(v[1]); ov.z = b2f(v[2]); ov.w = b2f(v[3]);
      mv.x = (mk < maskR[s4+0]) ? 1.0f : 0.0f;
      mv.y = (mk < maskR[s4+1]) ? 1.0f : 0.0f;
      mv.z = (mk < maskR[s4+2]) ? 1.0f : 0.0f;
      mv.w = (mk < maskR[s4+3]) ? 1.0f : 0.0f;
      *(float4*)(ob + cgl*S_ + s4) = ov;
      *(float4*)(om + cgl*S_ + s4) = mv;
    }
  }
}

extern "C" void kernel_launch(void* const* d_in, const int* in_sizes, int n_in,
                              void* d_out, int out_size, void* d_ws, size_t ws_size,
                              hipStream_t stream){
  const float* x    = (const float*)d_in[0];
  const int*   idx  = (const int*)d_in[1];
  const float* wgt  = (const float*)d_in[2];
  const float* bias = (const float*)d_in[3];
  const int*   rate = (const int*)d_in[4];

  char* ws = (char*)d_ws;
  short* xT        = (short*)ws;                 // 8 MB token-major bf16
  short* wT2       = (short*)(ws + 8388608);     // 1 MB tiled weights [r][kc][n][k32]
  int*   segBucket = (int*)  (ws + 9437184);     // 64 KB (128 segs x 128)
  int*   segCnt    = (int*)  (ws + 9502720);     // 4 KB  (128 segs x 8)

  float* outx    = (float*)d_out;
  float* outm    = outx + (B_*C_*S_);
  float* idx_out = outx + 2*(B_*C_*S_);

  k_pre <<<1216, 256, 0, stream>>>(x, xT, wgt, wT2, idx, segCnt, segBucket, idx_out);
  k_main<<<512,  256, 0, stream>>>(xT, wT2, bias, segCnt, segBucket, rate, outx, outm);
}